// Round 12
// baseline (285.171 us; speedup 1.0000x reference)
//
#include <hip/hip_runtime.h>

#define D 128
#define OUTC 64
#define EC 256      // edge chunks for CSR counting sort

typedef float floatx4 __attribute__((ext_vector_type(4)));
typedef short short8 __attribute__((ext_vector_type(8)));

// ---------- helpers ----------
__device__ inline unsigned short f2bf(float f) {
  unsigned int u = __float_as_uint(f);
  unsigned int r = (u + 0x7FFF + ((u >> 16) & 1)) >> 16;  // RNE
  return (unsigned short)r;
}
__device__ inline float bf2f(unsigned short u) {
  return __uint_as_float(((unsigned int)u) << 16);
}

// swizzled LDS element offset for [row][128] bf16 tiles (16B-chunk XOR, T2/G4)
__device__ inline int swz(int row, int k) { return row * 128 + (k ^ ((row & 7) << 3)); }

// ---------------- prep: weights -> transposed bf16 ----------------
__global__ __launch_bounds__(256) void k_prepw(const float* __restrict__ Wg, const float* __restrict__ Wl,
                                               const float* __restrict__ Wp,
                                               unsigned short* __restrict__ Wgt, unsigned short* __restrict__ Wlt,
                                               unsigned short* __restrict__ Wpt) {
  int u = blockIdx.x * 256 + threadIdx.x;
  const int W1 = 3 * D * D;
  if (u < W1) {
    int i = u / (D * D), rem = u % (D * D);
    int k = rem / D, n = rem % D;            // consecutive u -> consecutive n: coalesced reads
    Wgt[i * D * D + n * D + k] = f2bf(Wg[u]);
  } else if (u < 2 * W1) {
    int v = u - W1;
    int i = v / (D * D), rem = v % (D * D);
    int k = rem / D, n = rem % D;
    Wlt[i * D * D + n * D + k] = f2bf(Wl[v]);
  } else if (u < 2 * W1 + D * OUTC) {
    int v = u - 2 * W1;
    int k = v / OUTC, n = v % OUTC;
    Wpt[n * D + k] = f2bf(Wp[v]);
  }
}

// ================= atomic-free CSR build (bucket counting sort) =================
// bucket(node) = node >> 8 ; nbuk = ceil(N/256) <= 256

__global__ __launch_bounds__(256) void k_bh(const int* __restrict__ dst, int* __restrict__ bh,
                                            int E, int nbuk, int chk) {
  __shared__ int hist[256];
  int t = threadIdx.x, c = blockIdx.x;
  hist[t] = 0;
  __syncthreads();
  int s = c * chk, e = min(E, s + chk);
  for (int j = s + t; j < e; j += 256)
    atomicAdd(&hist[dst[j] >> 8], 1);
  __syncthreads();
  if (t < nbuk) bh[t * EC + c] = hist[t];
}

__device__ inline int block_scan4(int4 v, int t, int* total) {
  int s = v.x + v.y + v.z + v.w;
  int lane = t & 63, w = t >> 6;
  int incl = s;
  #pragma unroll
  for (int off = 1; off < 64; off <<= 1) {
    int nb = __shfl_up(incl, off);
    if (lane >= off) incl += nb;
  }
  __shared__ int wsum[4];
  if (lane == 63) wsum[w] = incl;
  __syncthreads();
  int woff = 0;
  #pragma unroll
  for (int k = 0; k < 3; ++k) if (w > k) woff += wsum[k];
  if (total) *total = wsum[0] + wsum[1] + wsum[2] + wsum[3];
  return woff + incl - s;
}

__global__ __launch_bounds__(256) void k_gscan1(int* __restrict__ arr, int* __restrict__ bsum, int n) {
  int t = threadIdx.x;
  int i0 = blockIdx.x * 1024 + t * 4;
  int4 v = make_int4(0, 0, 0, 0);
  if (i0 + 3 < n) v = *(const int4*)(arr + i0);
  else {
    if (i0 < n) v.x = arr[i0];
    if (i0 + 1 < n) v.y = arr[i0 + 1];
    if (i0 + 2 < n) v.z = arr[i0 + 2];
    if (i0 + 3 < n) v.w = arr[i0 + 3];
  }
  int total;
  int e = block_scan4(v, t, &total);
  if (i0 < n) {
    int4 o;
    o.x = e; o.y = e + v.x; o.z = o.y + v.y; o.w = o.z + v.z;
    if (i0 + 3 < n) *(int4*)(arr + i0) = o;
    else {
      arr[i0] = o.x;
      if (i0 + 1 < n) arr[i0 + 1] = o.y;
      if (i0 + 2 < n) arr[i0 + 2] = o.z;
    }
  }
  if (t == 0) bsum[blockIdx.x] = total;
}

__global__ __launch_bounds__(256) void k_gscan2(int* __restrict__ bsum, int nb) {
  int t = threadIdx.x;
  int i0 = t * 4;
  int4 v = make_int4(0, 0, 0, 0);
  if (i0 + 3 < nb) v = *(const int4*)(bsum + i0);
  else {
    if (i0 < nb) v.x = bsum[i0];
    if (i0 + 1 < nb) v.y = bsum[i0 + 1];
    if (i0 + 2 < nb) v.z = bsum[i0 + 2];
    if (i0 + 3 < nb) v.w = bsum[i0 + 3];
  }
  int e = block_scan4(v, t, nullptr);
  if (i0 < nb) {
    bsum[i0] = e;
    if (i0 + 1 < nb) bsum[i0 + 1] = e + v.x;
    if (i0 + 2 < nb) bsum[i0 + 2] = e + v.x + v.y;
    if (i0 + 3 < nb) bsum[i0 + 3] = e + v.x + v.y + v.z;
  }
}

// Pass C: scatter edges (packed: src | (dst&255)<<24) into bucket-partitioned array
__global__ __launch_bounds__(256) void k_scatter(const int* __restrict__ src, const int* __restrict__ dst,
                                                 const int* __restrict__ bhs, const int* __restrict__ bsum,
                                                 unsigned int* __restrict__ ebuk, int E, int nbuk, int chk) {
  __shared__ int cur[256];
  int t = threadIdx.x, c = blockIdx.x;
  if (t < nbuk) {
    int idx = t * EC + c;
    cur[t] = bhs[idx] + bsum[idx >> 10];
  }
  __syncthreads();
  int s = c * chk, e = min(E, s + chk);
  for (int j = s + t; j < e; j += 256) {
    int d = dst[j];
    int pos = atomicAdd(&cur[d >> 8], 1);
    ebuk[pos] = (unsigned int)src[j] | ((unsigned int)(d & 255) << 24);
  }
}

// Pass D: per-bucket CSR finalize
__global__ __launch_bounds__(256) void k_csr(const unsigned int* __restrict__ ebuk, const int* __restrict__ bhs,
                                             const int* __restrict__ bsum,
                                             int* __restrict__ rowstart, int* __restrict__ csr,
                                             float* __restrict__ dinv, int E, int N, int nbuk) {
  __shared__ int cnt[256];
  __shared__ int wsum[4];
  int t = threadIdx.x, b = blockIdx.x;
  int si = b * EC;
  int s = bhs[si] + bsum[si >> 10];
  int e;
  if (b + 1 < nbuk) { int ei_ = (b + 1) * EC; e = bhs[ei_] + bsum[ei_ >> 10]; }
  else e = E;
  cnt[t] = 0;
  __syncthreads();
  for (int j = s + t; j < e; j += 256)
    atomicAdd(&cnt[ebuk[j] >> 24], 1);
  __syncthreads();
  int v = cnt[t];
  int lane = t & 63, w = t >> 6;
  int incl = v;
  #pragma unroll
  for (int off = 1; off < 64; off <<= 1) {
    int nb = __shfl_up(incl, off);
    if (lane >= off) incl += nb;
  }
  if (lane == 63) wsum[w] = incl;
  __syncthreads();
  int woff = 0;
  #pragma unroll
  for (int k = 0; k < 3; ++k) if (w > k) woff += wsum[k];
  int rs = s + woff + incl - v;   // global exclusive prefix
  int node = (b << 8) + t;
  __syncthreads();
  cnt[t] = rs;                    // reuse as cursor
  if (node < N) {
    rowstart[node] = rs;
    dinv[node] = rsqrtf((float)v + 1.0f);
  }
  if (node == 0) rowstart[N] = E;
  __syncthreads();
  for (int j = s + t; j < e; j += 256) {
    unsigned int ed = ebuk[j];
    int pos = atomicAdd(&cnt[ed >> 24], 1);
    csr[pos] = (int)(ed & 0xFFFFFFu);
  }
}

// ---------------- MFMA dual GEMM (layer 0): reads x f32 directly; hg2 = dinv*(A@Wg), hl = A@Wl + bg + bl ----------------
__global__ __launch_bounds__(256) void k_dual(const float* __restrict__ x,
                                              const unsigned short* __restrict__ Wgt,
                                              const unsigned short* __restrict__ Wlt,
                                              const float* __restrict__ bg, const float* __restrict__ bl,
                                              const float* __restrict__ dinv,
                                              unsigned short* __restrict__ hg, unsigned short* __restrict__ hl, int M) {
  __shared__ unsigned short As[64 * 128];   // 16 KB
  __shared__ unsigned short Bs[128 * 128];  // 32 KB
  __shared__ float sdinv[64];
  int tid = threadIdx.x;
  int row0 = blockIdx.x * 64;

  if (tid < 64) sdinv[tid] = (row0 + tid < M) ? dinv[row0 + tid] : 0.f;
  // stage A: f32 -> bf16 inline
  {
    int r = tid >> 2;
    int row = row0 + r;
    bool valid = row < M;
    const float* src = x + (size_t)row * D;
    #pragma unroll
    for (int j = 0; j < 4; ++j) {
      int k0 = ((tid & 3) + j * 4) * 8;
      float4 va = make_float4(0.f, 0.f, 0.f, 0.f), vb = va;
      if (valid) { va = *(const float4*)(src + k0); vb = *(const float4*)(src + k0 + 4); }
      unsigned short hv[8];
      hv[0] = f2bf(va.x); hv[1] = f2bf(va.y); hv[2] = f2bf(va.z); hv[3] = f2bf(va.w);
      hv[4] = f2bf(vb.x); hv[5] = f2bf(vb.y); hv[6] = f2bf(vb.z); hv[7] = f2bf(vb.w);
      *(short8*)&As[swz(r, k0)] = *(const short8*)hv;
    }
  }
  #pragma unroll
  for (int j = 0; j < 8; ++j) {
    int idx = tid + j * 256;
    int nr = idx >> 4, c = idx & 15;
    *(short8*)&Bs[swz(nr, c * 8)] = *(const short8*)(Wgt + nr * D + c * 8);
  }
  __syncthreads();

  int lane = tid & 63, w = tid >> 6;
  int lrow = lane & 15, lk = (lane >> 4) * 8;

  short8 af[4][4];
  #pragma unroll
  for (int m = 0; m < 4; ++m) {
    int ar = lrow + m * 16;
    #pragma unroll
    for (int kk = 0; kk < 4; ++kk)
      af[m][kk] = *(const short8*)&As[swz(ar, lk + kk * 32)];
  }

  // ---- phase g (scaled by dinv[row]) ----
  {
    short8 bfg[2][4];
    #pragma unroll
    for (int n = 0; n < 2; ++n) {
      int br = w * 32 + n * 16 + lrow;
      #pragma unroll
      for (int kk = 0; kk < 4; ++kk)
        bfg[n][kk] = *(const short8*)&Bs[swz(br, lk + kk * 32)];
    }
    floatx4 acc[4][2];
    #pragma unroll
    for (int m = 0; m < 4; ++m)
      #pragma unroll
      for (int n = 0; n < 2; ++n)
        acc[m][n] = (floatx4)0.0f;
    #pragma unroll
    for (int kk = 0; kk < 4; ++kk)
      #pragma unroll
      for (int m = 0; m < 4; ++m)
        #pragma unroll
        for (int n = 0; n < 2; ++n)
          acc[m][n] = __builtin_amdgcn_mfma_f32_16x16x32_bf16(af[m][kk], bfg[n][kk], acc[m][n], 0, 0, 0);
    #pragma unroll
    for (int m = 0; m < 4; ++m)
      #pragma unroll
      for (int n = 0; n < 2; ++n) {
        int col = w * 32 + n * 16 + lrow;
        #pragma unroll
        for (int reg = 0; reg < 4; ++reg) {
          int lr = m * 16 + (lane >> 4) * 4 + reg;
          int row = row0 + lr;
          if (row < M) hg[(size_t)row * D + col] = f2bf(sdinv[lr] * acc[m][n][reg]);
        }
      }
  }
  __syncthreads();
  #pragma unroll
  for (int j = 0; j < 8; ++j) {
    int idx = tid + j * 256;
    int nr = idx >> 4, c = idx & 15;
    *(short8*)&Bs[swz(nr, c * 8)] = *(const short8*)(Wlt + nr * D + c * 8);
  }
  __syncthreads();
  // ---- phase l (+ folded biases) ----
  {
    short8 bfl[2][4];
    #pragma unroll
    for (int n = 0; n < 2; ++n) {
      int br = w * 32 + n * 16 + lrow;
      #pragma unroll
      for (int kk = 0; kk < 4; ++kk)
        bfl[n][kk] = *(const short8*)&Bs[swz(br, lk + kk * 32)];
    }
    floatx4 acc[4][2];
    #pragma unroll
    for (int m = 0; m < 4; ++m)
      #pragma unroll
      for (int n = 0; n < 2; ++n)
        acc[m][n] = (floatx4)0.0f;
    #pragma unroll
    for (int kk = 0; kk < 4; ++kk)
      #pragma unroll
      for (int m = 0; m < 4; ++m)
        #pragma unroll
        for (int n = 0; n < 2; ++n)
          acc[m][n] = __builtin_amdgcn_mfma_f32_16x16x32_bf16(af[m][kk], bfl[n][kk], acc[m][n], 0, 0, 0);
    #pragma unroll
    for (int m = 0; m < 4; ++m)
      #pragma unroll
      for (int n = 0; n < 2; ++n) {
        int col = w * 32 + n * 16 + lrow;
        float bias = bg[col] + bl[col];
        #pragma unroll
        for (int reg = 0; reg < 4; ++reg) {
          int row = row0 + m * 16 + (lane >> 4) * 4 + reg;
          if (row < M) hl[(size_t)row * D + col] = f2bf(acc[m][n][reg] + bias);
        }
      }
  }
}

// ---------------- aggregation (+ fused BN partial stats): 16 nodes/block, 4/wave ----------------
// Two edges per gather instruction: lanes 0-31 fetch edge A's row, lanes 32-63 edge B's.
// Each lane loads uint2 (8B = 4 channels); 8 slots => 16 edges in flight (covers degree~12 in 1 group).
#define ACC4(A, P) { A.x += __uint_as_float((P).x << 16); A.y += __uint_as_float((P).x & 0xFFFF0000u); \
                     A.z += __uint_as_float((P).y << 16); A.w += __uint_as_float((P).y & 0xFFFF0000u); }
__global__ __launch_bounds__(256) void k_agg(const unsigned short* __restrict__ hg2, unsigned short* __restrict__ pre,
                                             const int* __restrict__ rowstart, const int* __restrict__ csr,
                                             const float* __restrict__ dinv,
                                             float* __restrict__ partial, int n) {
  int t = threadIdx.x, b = blockIdx.x;
  int w = t >> 6, lane = t & 63;
  int q = lane & 31;         // channel group: channels 4q..4q+3
  int half = lane >> 5;      // 0 or 1: which edge of the pair this half-wave fetches
  const uint2* base = (const uint2*)hg2;   // row stride = 32 uint2 (256B)
  uint2* prew = (uint2*)pre;
  float ss0 = 0.f, ss1 = 0.f, ss2 = 0.f, ss3 = 0.f;
  float sq0 = 0.f, sq1 = 0.f, sq2 = 0.f, sq3 = 0.f;
  int node0 = b * 16 + w * 4;
  #pragma unroll 1
  for (int k = 0; k < 4; ++k) {
    int node = node0 + k;
    if (node >= n) break;
    int s = rowstart[node], e = rowstart[node + 1];
    float dn = dinv[node];
    uint2 ps = base[(size_t)node * 32 + q];       // hg2 self = dinv*hg (same addr both halves: broadcast)
    uint2 oldw = prew[(size_t)node * 32 + q];
    floatx4 a0 = (floatx4)0.0f, a1 = (floatx4)0.0f, a2 = (floatx4)0.0f, a3 = (floatx4)0.0f;
    floatx4 a4 = (floatx4)0.0f, a5 = (floatx4)0.0f, a6 = (floatx4)0.0f, a7 = (floatx4)0.0f;
    int j = s;
    for (; j + 16 <= e; j += 16) {
      int jj = j + (half << 3);
      int i0 = csr[jj],     i1 = csr[jj + 1], i2 = csr[jj + 2], i3 = csr[jj + 3];
      int i4 = csr[jj + 4], i5 = csr[jj + 5], i6 = csr[jj + 6], i7 = csr[jj + 7];
      uint2 p0 = base[(size_t)i0 * 32 + q];
      uint2 p1 = base[(size_t)i1 * 32 + q];
      uint2 p2 = base[(size_t)i2 * 32 + q];
      uint2 p3 = base[(size_t)i3 * 32 + q];
      uint2 p4 = base[(size_t)i4 * 32 + q];
      uint2 p5 = base[(size_t)i5 * 32 + q];
      uint2 p6 = base[(size_t)i6 * 32 + q];
      uint2 p7 = base[(size_t)i7 * 32 + q];
      ACC4(a0, p0) ACC4(a1, p1) ACC4(a2, p2) ACC4(a3, p3)
      ACC4(a4, p4) ACC4(a5, p5) ACC4(a6, p6) ACC4(a7, p7)
    }
    if (j < e) {
      int rem = e - j;             // 1..15
      int last = e - 1;
      int jj = j + (half << 3);
      int hb = half << 3;
      int i0 = csr[min(jj, last)],     i1 = csr[min(jj + 1, last)];
      int i2 = csr[min(jj + 2, last)], i3 = csr[min(jj + 3, last)];
      int i4 = csr[min(jj + 4, last)], i5 = csr[min(jj + 5, last)];
      int i6 = csr[min(jj + 6, last)], i7 = csr[min(jj + 7, last)];
      uint2 p0 = base[(size_t)i0 * 32 + q];
      uint2 p1 = base[(size_t)i1 * 32 + q];
      uint2 p2 = base[(size_t)i2 * 32 + q];
      uint2 p3 = base[(size_t)i3 * 32 + q];
      uint2 p4 = base[(size_t)i4 * 32 + q];
      uint2 p5 = base[(size_t)i5 * 32 + q];
      uint2 p6 = base[(size_t)i6 * 32 + q];
      uint2 p7 = base[(size_t)i7 * 32 + q];
      if (hb + 0 < rem) ACC4(a0, p0)
      if (hb + 1 < rem) ACC4(a1, p1)
      if (hb + 2 < rem) ACC4(a2, p2)
      if (hb + 3 < rem) ACC4(a3, p3)
      if (hb + 4 < rem) ACC4(a4, p4)
      if (hb + 5 < rem) ACC4(a5, p5)
      if (hb + 6 < rem) ACC4(a6, p6)
      if (hb + 7 < rem) ACC4(a7, p7)
    }
    floatx4 a = ((a0 + a1) + (a2 + a3)) + ((a4 + a5) + (a6 + a7));
    // combine the two half-wave partials (lane L <-> lane L^32 hold same channels)
    a.x += __shfl_xor(a.x, 32);
    a.y += __shfl_xor(a.y, 32);
    a.z += __shfl_xor(a.z, 32);
    a.w += __shfl_xor(a.w, 32);
    float h0 = __uint_as_float(ps.x << 16);
    float h1 = __uint_as_float(ps.x & 0xFFFF0000u);
    float h2 = __uint_as_float(ps.y << 16);
    float h3 = __uint_as_float(ps.y & 0xFFFF0000u);
    float o0 = __uint_as_float(oldw.x << 16);
    float o1 = __uint_as_float(oldw.x & 0xFFFF0000u);
    float o2 = __uint_as_float(oldw.y << 16);
    float o3 = __uint_as_float(oldw.y & 0xFFFF0000u);
    float v0 = dn * (a.x + h0) + o0;   // old already includes bg+bl
    float v1 = dn * (a.y + h1) + o1;
    float v2 = dn * (a.z + h2) + o2;
    float v3 = dn * (a.w + h3) + o3;
    if (half == 0) {
      uint2 pw;
      pw.x = (unsigned int)f2bf(v0) | ((unsigned int)f2bf(v1) << 16);
      pw.y = (unsigned int)f2bf(v2) | ((unsigned int)f2bf(v3) << 16);
      prew[(size_t)node * 32 + q] = pw;
      ss0 += v0; ss1 += v1; ss2 += v2; ss3 += v3;       // stats from f32 pre-rounding values
      sq0 += v0 * v0; sq1 += v1 * v1; sq2 += v2 * v2; sq3 += v3 * v3;
    }
  }
  __shared__ float sm[4][128], sq[4][128];
  if (half == 0) {
    int c = q * 4;
    sm[w][c] = ss0; sm[w][c + 1] = ss1; sm[w][c + 2] = ss2; sm[w][c + 3] = ss3;
    sq[w][c] = sq0; sq[w][c + 1] = sq1; sq[w][c + 2] = sq2; sq[w][c + 3] = sq3;
  }
  __syncthreads();
  if (t < 128) {
    float s = (sm[0][t] + sm[1][t]) + (sm[2][t] + sm[3][t]);
    float qv = (sq[0][t] + sq[1][t]) + (sq[2][t] + sq[3][t]);
    partial[(size_t)b * 256 + t] = s;          // row-major: contiguous 1KB per block
    partial[(size_t)b * 256 + 128 + t] = qv;
  }
}

// ---------------- BN reduce stage A: 64 blocks, coalesced column sums over partial rows ----------------
__global__ __launch_bounds__(256) void k_fina(const float* __restrict__ partial, float* __restrict__ p2, int nab) {
  int t = threadIdx.x, b = blockIdx.x;
  float s = 0.f;
  for (int i = b; i < nab; i += 64)
    s += partial[(size_t)i * 256 + t];
  p2[(size_t)b * 256 + t] = s;
}

// ---------------- BN reduce stage B: 1 block, final sum + affine ----------------
__global__ __launch_bounds__(256) void k_finb(const float* __restrict__ p2,
                                              const float* __restrict__ gamma, const float* __restrict__ beta,
                                              float* __restrict__ ab, float invN) {
  int t = threadIdx.x;
  float s = 0.f;
  #pragma unroll
  for (int b = 0; b < 64; ++b)
    s += p2[(size_t)b * 256 + t];
  __shared__ float red[256];
  red[t] = s;
  __syncthreads();
  if (t < 128) {
    float mean = red[t] * invN;
    float var = red[128 + t] * invN - mean * mean;
    float inv = rsqrtf(var + 1e-5f);
    float g = gamma[t];
    ab[t] = g * inv;
    ab[128 + t] = beta[t] - mean * inv * g;
  }
}

// ---------------- fused: h=BN+ReLU(pre bf16); out(+)=h@Wp(+bp); hg2=dinv*(h@Wg_next); hl=h@Wl_next+biases ----------------
template<bool FIRST>
__global__ __launch_bounds__(256) void k_fused(const unsigned short* __restrict__ pre, const float* __restrict__ ab,
                                               const unsigned short* __restrict__ Wpt, const float* __restrict__ bp,
                                               const unsigned short* __restrict__ Wgt,
                                               const unsigned short* __restrict__ Wlt,
                                               const float* __restrict__ bgn, const float* __restrict__ bln,
                                               const float* __restrict__ dinv,
                                               float* __restrict__ out, unsigned short* __restrict__ hg,
                                               unsigned short* __restrict__ hl, int M) {
  __shared__ unsigned short As[64 * 128];   // 16 KB
  __shared__ unsigned short Bs[128 * 128];  // 32 KB (Wp then Wg then Wl)
  __shared__ float sdinv[64];
  int tid = threadIdx.x;
  int row0 = blockIdx.x * 64;

  if (tid < 64) sdinv[tid] = (row0 + tid < M) ? dinv[row0 + tid] : 0.f;
  // stage A: h tile from bf16 pre + BN affine + relu (swizzled)
  {
    int r = tid >> 2, qq = tid & 3;
    int row = row0 + r;
    bool valid = row < M;
    const unsigned short* Pp = pre + (size_t)row * D;
    #pragma unroll
    for (int ch = 0; ch < 4; ++ch) {
      int k0 = qq * 32 + ch * 8;
      short8 pv = {0, 0, 0, 0, 0, 0, 0, 0};
      if (valid) pv = *(const short8*)(Pp + k0);
      float4 a0 = *(const float4*)(ab + k0),        a1 = *(const float4*)(ab + k0 + 4);
      float4 b0 = *(const float4*)(ab + 128 + k0),  b1 = *(const float4*)(ab + 128 + k0 + 4);
      float av[8] = {a0.x, a0.y, a0.z, a0.w, a1.x, a1.y, a1.z, a1.w};
      float bv[8] = {b0.x, b0.y, b0.z, b0.w, b1.x, b1.y, b1.z, b1.w};
      unsigned short hv[8];
      #pragma unroll
      for (int jj = 0; jj < 8; ++jj) {
        float f = bf2f((unsigned short)pv[jj]);
        hv[jj] = f2bf(fmaxf(f * av[jj] + bv[jj], 0.f));
      }
      *(short8*)&As[swz(r, k0)] = *(const short8*)hv;
    }
  }
  // stage Wp^T [64][128]
  #pragma unroll
  for (int j = 0; j < 4; ++j) {
    int idx = tid + j * 256;
    int nr = idx >> 4, c = idx & 15;
    *(short8*)&Bs[swz(nr, c * 8)] = *(const short8*)(Wpt + nr * D + c * 8);
  }
  __syncthreads();

  int lane = tid & 63, w = tid >> 6;
  int lrow = lane & 15, lk = (lane >> 4) * 8;

  short8 af[4][4];
  #pragma unroll
  for (int m = 0; m < 4; ++m) {
    int ar = lrow + m * 16;
    #pragma unroll
    for (int kk = 0; kk < 4; ++kk)
      af[m][kk] = *(const short8*)&As[swz(ar, lk + kk * 32)];
  }

  // ---- phase P: out ----
  {
    short8 bfr[4];
    int br = w * 16 + lrow;
    #pragma unroll
    for (int kk = 0; kk < 4; ++kk)
      bfr[kk] = *(const short8*)&Bs[swz(br, lk + kk * 32)];
    floatx4 acc[4];
    #pragma unroll
    for (int m = 0; m < 4; ++m) acc[m] = (floatx4)0.0f;
    #pragma unroll
    for (int kk = 0; kk < 4; ++kk)
      #pragma unroll
      for (int m = 0; m < 4; ++m)
        acc[m] = __builtin_amdgcn_mfma_f32_16x16x32_bf16(af[m][kk], bfr[kk], acc[m], 0, 0, 0);
    int col = w * 16 + lrow;
    float bpv = FIRST ? bp[col] : 0.f;
    #pragma unroll
    for (int m = 0; m < 4; ++m)
      #pragma unroll
      for (int reg = 0; reg < 4; ++reg) {
        int row = row0 + m * 16 + (lane >> 4) * 4 + reg;
        if (row < M) {
          float* op = &out[(size_t)row * OUTC + col];
          float v = acc[m][reg] + bpv;
          if (!FIRST) v += *op;
          *op = v;
        }
      }
  }
  __syncthreads();
  // stage Wg^T
  #pragma unroll
  for (int j = 0; j < 8; ++j) {
    int idx = tid + j * 256;
    int nr = idx >> 4, c = idx & 15;
    *(short8*)&Bs[swz(nr, c * 8)] = *(const short8*)(Wgt + nr * D + c * 8);
  }
  __syncthreads();
  // ---- phase G: hg2 = dinv * (h@Wg) ----
  {
    short8 bfg[2][4];
    #pragma unroll
    for (int n = 0; n < 2; ++n) {
      int br = w * 32 + n * 16 + lrow;
      #pragma unroll
      for (int kk = 0; kk < 4; ++kk)
        bfg[n][kk] = *(const short8*)&Bs[swz(br, lk + kk * 32)];
    }
    floatx4 acc[4][2];
    #pragma unroll
    for (int m = 0; m < 4; ++m)
      #pragma unroll
      for (int n = 0; n < 2; ++n)
        acc[m][n] = (floatx4)0.0f;
    #pragma unroll
    for (int kk = 0; kk < 4; ++kk)
      #pragma unroll
      for (int m = 0; m < 4; ++m)
        #pragma unroll
        for (int n = 0; n < 2; ++n)
          acc[m][n] = __builtin_amdgcn_mfma_f32_16x16x32_bf16(af[m][kk], bfg[n][kk], acc[m][n], 0, 0, 0);
    #pragma unroll
    for (int m = 0; m < 4; ++m)
      #pragma unroll
      for (int n = 0; n < 2; ++n) {
        int col = w * 32 + n * 16 + lrow;
        #pragma unroll
        for (int reg = 0; reg < 4; ++reg) {
          int lr = m * 16 + (lane >> 4) * 4 + reg;
          int row = row0 + lr;
          if (row < M) hg[(size_t)row * D + col] = f2bf(sdinv[lr] * acc[m][n][reg]);
        }
      }
  }
  __syncthreads();
  // stage Wl^T
  #pragma unroll
  for (int j = 0; j < 8; ++j) {
    int idx = tid + j * 256;
    int nr = idx >> 4, c = idx & 15;
    *(short8*)&Bs[swz(nr, c * 8)] = *(const short8*)(Wlt + nr * D + c * 8);
  }
  __syncthreads();
  // ---- phase L: hl (in-place over pre rows of THIS block only) ----
  {
    short8 bfl[2][4];
    #pragma unroll
    for (int n = 0; n < 2; ++n) {
      int br = w * 32 + n * 16 + lrow;
      #pragma unroll
      for (int kk = 0; kk < 4; ++kk)
        bfl[n][kk] = *(const short8*)&Bs[swz(br, lk + kk * 32)];
    }
    floatx4 acc[4][2];
    #pragma unroll
    for (int m = 0; m < 4; ++m)
      #pragma unroll
      for (int n = 0; n < 2; ++n)
        acc[m][n] = (floatx4)0.0f;
    #pragma unroll
    for (int kk = 0; kk < 4; ++kk)
      #pragma unroll
      for (int m = 0; m < 4; ++m)
        #pragma unroll
        for (int n = 0; n < 2; ++n)
          acc[m][n] = __builtin_amdgcn_mfma_f32_16x16x32_bf16(af[m][kk], bfl[n][kk], acc[m][n], 0, 0, 0);
    #pragma unroll
    for (int m = 0; m < 4; ++m)
      #pragma unroll
      for (int n = 0; n < 2; ++n) {
        int col = w * 32 + n * 16 + lrow;
        float bias = bgn[col] + bln[col];
        #pragma unroll
        for (int reg = 0; reg < 4; ++reg) {
          int row = row0 + m * 16 + (lane >> 4) * 4 + reg;
          if (row < M) hl[(size_t)row * D + col] = f2bf(acc[m][n][reg] + bias);
        }
      }
  }
}

// ---------------- final layer: h=BN+ReLU(pre bf16); out += h@Wp ----------------
__global__ __launch_bounds__(256) void k_out(const unsigned short* __restrict__ pre, const float* __restrict__ ab,
                                             const unsigned short* __restrict__ Wpt,
                                             float* __restrict__ out, int M) {
  __shared__ unsigned short As[64 * 128];   // 16 KB
  __shared__ unsigned short Bs[OUTC * 128]; // 16 KB
  int tid = threadIdx.x;
  int row0 = blockIdx.x * 64;

  {
    int r = tid >> 2, qq = tid & 3;
    int row = row0 + r;
    bool valid = row < M;
    const unsigned short* Pp = pre + (size_t)row * D;
    #pragma unroll
    for (int ch = 0; ch < 4; ++ch) {
      int k0 = qq * 32 + ch * 8;
      short8 pv = {0, 0, 0, 0, 0, 0, 0, 0};
      if (valid) pv = *(const short8*)(Pp + k0);
      float4 a0 = *(const float4*)(ab + k0),        a1 = *(const float4*)(ab + k0 + 4);
      float4 b0 = *(const float4*)(ab + 128 + k0),  b1 = *(const float4*)(ab + 128 + k0 + 4);
      float av[8] = {a0.x, a0.y, a0.z, a0.w, a1.x, a1.y, a1.z, a1.w};
      float bv[8] = {b0.x, b0.y, b0.z, b0.w, b1.x, b1.y, b1.z, b1.w};
      unsigned short hv[8];
      #pragma unroll
      for (int jj = 0; jj < 8; ++jj) {
        float f = bf2f((unsigned short)pv[jj]);
        hv[jj] = f2bf(fmaxf(f * av[jj] + bv[jj], 0.f));
      }
      *(short8*)&As[swz(r, k0)] = *(const short8*)hv;
    }
  }
  #pragma unroll
  for (int j = 0; j < 4; ++j) {
    int idx = tid + j * 256;
    int nr = idx >> 4, c = idx & 15;
    *(short8*)&Bs[swz(nr, c * 8)] = *(const short8*)(Wpt + nr * D + c * 8);
  }
  __syncthreads();

  int lane = tid & 63, w = tid >> 6;
  int lrow = lane & 15, lk = (lane >> 4) * 8;

  short8 af[4][4];
  #pragma unroll
  for (int m = 0; m < 4; ++m) {
    int ar = lrow + m * 16;
    #pragma unroll
    for (int kk = 0; kk < 4; ++kk)
      af[m][kk] = *(const short8*)&As[swz(ar, lk + kk * 32)];
  }
  short8 bfr[4];
  {
    int br = w * 16 + lrow;
    #pragma unroll
    for (int kk = 0; kk < 4; ++kk)
      bfr[kk] = *(const short8*)&Bs[swz(br, lk + kk * 32)];
  }
  floatx4 acc[4];
  #pragma unroll
  for (int m = 0; m < 4; ++m) acc[m] = (floatx4)0.0f;
  #pragma unroll
  for (int kk = 0; kk < 4; ++kk)
    #pragma unroll
    for (int m = 0; m < 4; ++m)
      acc[m] = __builtin_amdgcn_mfma_f32_16x16x32_bf16(af[m][kk], bfr[kk], acc[m], 0, 0, 0);

  int col = w * 16 + lrow;
  #pragma unroll
  for (int m = 0; m < 4; ++m)
    #pragma unroll
    for (int reg = 0; reg < 4; ++reg) {
      int row = row0 + m * 16 + (lane >> 4) * 4 + reg;
      if (row < M) {
        float* op = &out[(size_t)row * OUTC + col];
        *op = *op + acc[m][reg];
      }
    }
}

extern "C" void kernel_launch(void* const* d_in, const int* in_sizes, int n_in,
                              void* d_out, int out_size, void* d_ws, size_t ws_size,
                              hipStream_t stream) {
  const float* x     = (const float*)d_in[0];
  const int*   ei    = (const int*)d_in[1];
  const float* Wg    = (const float*)d_in[2];
  const float* bg    = (const float*)d_in[3];
  const float* Wl    = (const float*)d_in[4];
  const float* bl    = (const float*)d_in[5];
  const float* gamma = (const float*)d_in[6];
  const float* beta  = (const float*)d_in[7];
  const float* Wp    = (const float*)d_in[8];
  const float* bp    = (const float*)d_in[9];
  float* out = (float*)d_out;

  int N = in_sizes[0] / D;
  int E = in_sizes[1] / 2;
  const int* srcp = ei;
  const int* dstp = ei + E;

  char* wsb = (char*)d_ws;
  size_t off = 0;
  auto alloc = [&](size_t bytes) {
    off = (off + 255) & ~(size_t)255;
    void* p = wsb + off;
    off += bytes;
    return p;
  };
  int nab = (N + 15) / 16;                 // k_agg blocks (16 nodes/block, 4/wave)
  float* dinv     = (float*)alloc((size_t)N * 4);
  int*   rowstart = (int*)alloc((size_t)(N + 1) * 4);
  int*   csr      = (int*)alloc((size_t)E * 4);
  int*   bh       = (int*)alloc((size_t)256 * EC * 4);
  unsigned int* ebuk = (unsigned int*)alloc((size_t)E * 4);
  int*   bsum     = (int*)alloc(1024 * 4);
  float* partial  = (float*)alloc((size_t)nab * 256 * 4);   // [block][256] row-major
  float* p2       = (float*)alloc((size_t)64 * 256 * 4);
  float* ab       = (float*)alloc(3 * 256 * 4);
  unsigned short* hg  = (unsigned short*)alloc((size_t)N * D * 2);
  unsigned short* hl  = (unsigned short*)alloc((size_t)N * D * 2);
  unsigned short* Wgt = (unsigned short*)alloc(3 * D * D * 2);
  unsigned short* Wlt = (unsigned short*)alloc(3 * D * D * 2);
  unsigned short* Wpt = (unsigned short*)alloc(D * OUTC * 2);
  (void)ws_size; (void)n_in; (void)out_size;

  int wtotal = 2 * 3 * D * D + D * OUTC;
  k_prepw<<<(wtotal + 255) / 256, 256, 0, stream>>>(Wg, Wl, Wp, Wgt, Wlt, Wpt);

  // ---- CSR build (atomic-free counting sort) ----
  int nbuk = (N + 255) >> 8;
  int chk  = (E + EC - 1) / EC;
  k_bh<<<EC, 256, 0, stream>>>(dstp, bh, E, nbuk, chk);
  int sn  = nbuk * EC;
  int snb = (sn + 1023) >> 10;
  k_gscan1<<<snb, 256, 0, stream>>>(bh, bsum, sn);
  k_gscan2<<<1, 256, 0, stream>>>(bsum, snb);
  k_scatter<<<EC, 256, 0, stream>>>(srcp, dstp, bh, bsum, ebuk, E, nbuk, chk);
  k_csr<<<nbuk, 256, 0, stream>>>(ebuk, bh, bsum, rowstart, csr, dinv, E, N, nbuk);

  int mt = (N + 63) / 64;
  float invN = 1.0f / (float)N;

  // layer 0 GEMMs (reads x f32 directly)
  k_dual<<<mt, 256, 0, stream>>>(x, Wgt, Wlt, bg, bl, dinv, hg, hl, N);

  for (int i = 0; i < 3; ++i) {
    k_agg<<<nab, 256, 0, stream>>>(hg, hl, rowstart, csr, dinv, partial, N);
    k_fina<<<64, 256, 0, stream>>>(partial, p2, nab);
    k_finb<<<1, 256, 0, stream>>>(p2, gamma + (size_t)i * D, beta + (size_t)i * D, ab + i * 256, invN);
    if (i == 0)
      k_fused<true><<<mt, 256, 0, stream>>>(hl, ab + i * 256, Wpt, bp,
                                            Wgt + (size_t)(i + 1) * D * D, Wlt + (size_t)(i + 1) * D * D,
                                            bg + (size_t)(i + 1) * D, bl + (size_t)(i + 1) * D,
                                            dinv, out, hg, hl, N);
    else if (i == 1)
      k_fused<false><<<mt, 256, 0, stream>>>(hl, ab + i * 256, Wpt, bp,
                                             Wgt + (size_t)(i + 1) * D * D, Wlt + (size_t)(i + 1) * D * D,
                                             bg + (size_t)(i + 1) * D, bl + (size_t)(i + 1) * D,
                                             dinv, out, hg, hl, N);
    else
      k_out<<<mt, 256, 0, stream>>>(hl, ab + i * 256, Wpt, out, N);
  }
}

// Round 13
// 264.501 us; speedup vs baseline: 1.0781x; 1.0781x over previous
//
#include <hip/hip_runtime.h>

#define D 128
#define OUTC 64
#define EC 256      // edge chunks for CSR counting sort

typedef float floatx4 __attribute__((ext_vector_type(4)));
typedef short short8 __attribute__((ext_vector_type(8)));

// ---------- helpers ----------
__device__ inline unsigned short f2bf(float f) {
  unsigned int u = __float_as_uint(f);
  unsigned int r = (u + 0x7FFF + ((u >> 16) & 1)) >> 16;  // RNE
  return (unsigned short)r;
}
__device__ inline float bf2f(unsigned short u) {
  return __uint_as_float(((unsigned int)u) << 16);
}

// swizzled LDS element offset for [row][128] bf16 tiles (16B-chunk XOR, T2/G4)
__device__ inline int swz(int row, int k) { return row * 128 + (k ^ ((row & 7) << 3)); }

// ---------------- prep: weights -> transposed bf16 ----------------
__global__ __launch_bounds__(256) void k_prepw(const float* __restrict__ Wg, const float* __restrict__ Wl,
                                               const float* __restrict__ Wp,
                                               unsigned short* __restrict__ Wgt, unsigned short* __restrict__ Wlt,
                                               unsigned short* __restrict__ Wpt) {
  int u = blockIdx.x * 256 + threadIdx.x;
  const int W1 = 3 * D * D;
  if (u < W1) {
    int i = u / (D * D), rem = u % (D * D);
    int k = rem / D, n = rem % D;            // consecutive u -> consecutive n: coalesced reads
    Wgt[i * D * D + n * D + k] = f2bf(Wg[u]);
  } else if (u < 2 * W1) {
    int v = u - W1;
    int i = v / (D * D), rem = v % (D * D);
    int k = rem / D, n = rem % D;
    Wlt[i * D * D + n * D + k] = f2bf(Wl[v]);
  } else if (u < 2 * W1 + D * OUTC) {
    int v = u - 2 * W1;
    int k = v / OUTC, n = v % OUTC;
    Wpt[n * D + k] = f2bf(Wp[v]);
  }
}

// ================= atomic-free CSR build (bucket counting sort) =================
// bucket(node) = node >> 8 ; nbuk = ceil(N/256) <= 256

__global__ __launch_bounds__(256) void k_bh(const int* __restrict__ dst, int* __restrict__ bh,
                                            int E, int nbuk, int chk) {
  __shared__ int hist[256];
  int t = threadIdx.x, c = blockIdx.x;
  hist[t] = 0;
  __syncthreads();
  int s = c * chk, e = min(E, s + chk);
  for (int j = s + t; j < e; j += 256)
    atomicAdd(&hist[dst[j] >> 8], 1);
  __syncthreads();
  if (t < nbuk) bh[t * EC + c] = hist[t];
}

__device__ inline int block_scan4(int4 v, int t, int* total) {
  int s = v.x + v.y + v.z + v.w;
  int lane = t & 63, w = t >> 6;
  int incl = s;
  #pragma unroll
  for (int off = 1; off < 64; off <<= 1) {
    int nb = __shfl_up(incl, off);
    if (lane >= off) incl += nb;
  }
  __shared__ int wsum[4];
  if (lane == 63) wsum[w] = incl;
  __syncthreads();
  int woff = 0;
  #pragma unroll
  for (int k = 0; k < 3; ++k) if (w > k) woff += wsum[k];
  if (total) *total = wsum[0] + wsum[1] + wsum[2] + wsum[3];
  return woff + incl - s;
}

__global__ __launch_bounds__(256) void k_gscan1(int* __restrict__ arr, int* __restrict__ bsum, int n) {
  int t = threadIdx.x;
  int i0 = blockIdx.x * 1024 + t * 4;
  int4 v = make_int4(0, 0, 0, 0);
  if (i0 + 3 < n) v = *(const int4*)(arr + i0);
  else {
    if (i0 < n) v.x = arr[i0];
    if (i0 + 1 < n) v.y = arr[i0 + 1];
    if (i0 + 2 < n) v.z = arr[i0 + 2];
    if (i0 + 3 < n) v.w = arr[i0 + 3];
  }
  int total;
  int e = block_scan4(v, t, &total);
  if (i0 < n) {
    int4 o;
    o.x = e; o.y = e + v.x; o.z = o.y + v.y; o.w = o.z + v.z;
    if (i0 + 3 < n) *(int4*)(arr + i0) = o;
    else {
      arr[i0] = o.x;
      if (i0 + 1 < n) arr[i0 + 1] = o.y;
      if (i0 + 2 < n) arr[i0 + 2] = o.z;
    }
  }
  if (t == 0) bsum[blockIdx.x] = total;
}

__global__ __launch_bounds__(256) void k_gscan2(int* __restrict__ bsum, int nb) {
  int t = threadIdx.x;
  int i0 = t * 4;
  int4 v = make_int4(0, 0, 0, 0);
  if (i0 + 3 < nb) v = *(const int4*)(bsum + i0);
  else {
    if (i0 < nb) v.x = bsum[i0];
    if (i0 + 1 < nb) v.y = bsum[i0 + 1];
    if (i0 + 2 < nb) v.z = bsum[i0 + 2];
    if (i0 + 3 < nb) v.w = bsum[i0 + 3];
  }
  int e = block_scan4(v, t, nullptr);
  if (i0 < nb) {
    bsum[i0] = e;
    if (i0 + 1 < nb) bsum[i0 + 1] = e + v.x;
    if (i0 + 2 < nb) bsum[i0 + 2] = e + v.x + v.y;
    if (i0 + 3 < nb) bsum[i0 + 3] = e + v.x + v.y + v.z;
  }
}

// Pass C: scatter edges (packed: src | (dst&255)<<24) into bucket-partitioned array
__global__ __launch_bounds__(256) void k_scatter(const int* __restrict__ src, const int* __restrict__ dst,
                                                 const int* __restrict__ bhs, const int* __restrict__ bsum,
                                                 unsigned int* __restrict__ ebuk, int E, int nbuk, int chk) {
  __shared__ int cur[256];
  int t = threadIdx.x, c = blockIdx.x;
  if (t < nbuk) {
    int idx = t * EC + c;
    cur[t] = bhs[idx] + bsum[idx >> 10];
  }
  __syncthreads();
  int s = c * chk, e = min(E, s + chk);
  for (int j = s + t; j < e; j += 256) {
    int d = dst[j];
    int pos = atomicAdd(&cur[d >> 8], 1);
    ebuk[pos] = (unsigned int)src[j] | ((unsigned int)(d & 255) << 24);
  }
}

// Pass D: per-bucket CSR finalize
__global__ __launch_bounds__(256) void k_csr(const unsigned int* __restrict__ ebuk, const int* __restrict__ bhs,
                                             const int* __restrict__ bsum,
                                             int* __restrict__ rowstart, int* __restrict__ csr,
                                             float* __restrict__ dinv, int E, int N, int nbuk) {
  __shared__ int cnt[256];
  __shared__ int wsum[4];
  int t = threadIdx.x, b = blockIdx.x;
  int si = b * EC;
  int s = bhs[si] + bsum[si >> 10];
  int e;
  if (b + 1 < nbuk) { int ei_ = (b + 1) * EC; e = bhs[ei_] + bsum[ei_ >> 10]; }
  else e = E;
  cnt[t] = 0;
  __syncthreads();
  for (int j = s + t; j < e; j += 256)
    atomicAdd(&cnt[ebuk[j] >> 24], 1);
  __syncthreads();
  int v = cnt[t];
  int lane = t & 63, w = t >> 6;
  int incl = v;
  #pragma unroll
  for (int off = 1; off < 64; off <<= 1) {
    int nb = __shfl_up(incl, off);
    if (lane >= off) incl += nb;
  }
  if (lane == 63) wsum[w] = incl;
  __syncthreads();
  int woff = 0;
  #pragma unroll
  for (int k = 0; k < 3; ++k) if (w > k) woff += wsum[k];
  int rs = s + woff + incl - v;   // global exclusive prefix
  int node = (b << 8) + t;
  __syncthreads();
  cnt[t] = rs;                    // reuse as cursor
  if (node < N) {
    rowstart[node] = rs;
    dinv[node] = rsqrtf((float)v + 1.0f);
  }
  if (node == 0) rowstart[N] = E;
  __syncthreads();
  for (int j = s + t; j < e; j += 256) {
    unsigned int ed = ebuk[j];
    int pos = atomicAdd(&cnt[ed >> 24], 1);
    csr[pos] = (int)(ed & 0xFFFFFFu);
  }
}

// ---------------- MFMA dual GEMM (layer 0): reads x f32 directly; hg2 = dinv*(A@Wg), hl = A@Wl + bg + bl ----------------
__global__ __launch_bounds__(256) void k_dual(const float* __restrict__ x,
                                              const unsigned short* __restrict__ Wgt,
                                              const unsigned short* __restrict__ Wlt,
                                              const float* __restrict__ bg, const float* __restrict__ bl,
                                              const float* __restrict__ dinv,
                                              unsigned short* __restrict__ hg, unsigned short* __restrict__ hl, int M) {
  __shared__ unsigned short As[64 * 128];   // 16 KB
  __shared__ unsigned short Bs[128 * 128];  // 32 KB
  __shared__ float sdinv[64];
  int tid = threadIdx.x;
  int row0 = blockIdx.x * 64;

  if (tid < 64) sdinv[tid] = (row0 + tid < M) ? dinv[row0 + tid] : 0.f;
  // stage A: f32 -> bf16 inline
  {
    int r = tid >> 2;
    int row = row0 + r;
    bool valid = row < M;
    const float* src = x + (size_t)row * D;
    #pragma unroll
    for (int j = 0; j < 4; ++j) {
      int k0 = ((tid & 3) + j * 4) * 8;
      float4 va = make_float4(0.f, 0.f, 0.f, 0.f), vb = va;
      if (valid) { va = *(const float4*)(src + k0); vb = *(const float4*)(src + k0 + 4); }
      unsigned short hv[8];
      hv[0] = f2bf(va.x); hv[1] = f2bf(va.y); hv[2] = f2bf(va.z); hv[3] = f2bf(va.w);
      hv[4] = f2bf(vb.x); hv[5] = f2bf(vb.y); hv[6] = f2bf(vb.z); hv[7] = f2bf(vb.w);
      *(short8*)&As[swz(r, k0)] = *(const short8*)hv;
    }
  }
  #pragma unroll
  for (int j = 0; j < 8; ++j) {
    int idx = tid + j * 256;
    int nr = idx >> 4, c = idx & 15;
    *(short8*)&Bs[swz(nr, c * 8)] = *(const short8*)(Wgt + nr * D + c * 8);
  }
  __syncthreads();

  int lane = tid & 63, w = tid >> 6;
  int lrow = lane & 15, lk = (lane >> 4) * 8;

  short8 af[4][4];
  #pragma unroll
  for (int m = 0; m < 4; ++m) {
    int ar = lrow + m * 16;
    #pragma unroll
    for (int kk = 0; kk < 4; ++kk)
      af[m][kk] = *(const short8*)&As[swz(ar, lk + kk * 32)];
  }

  // ---- phase g (scaled by dinv[row]) ----
  {
    short8 bfg[2][4];
    #pragma unroll
    for (int n = 0; n < 2; ++n) {
      int br = w * 32 + n * 16 + lrow;
      #pragma unroll
      for (int kk = 0; kk < 4; ++kk)
        bfg[n][kk] = *(const short8*)&Bs[swz(br, lk + kk * 32)];
    }
    floatx4 acc[4][2];
    #pragma unroll
    for (int m = 0; m < 4; ++m)
      #pragma unroll
      for (int n = 0; n < 2; ++n)
        acc[m][n] = (floatx4)0.0f;
    #pragma unroll
    for (int kk = 0; kk < 4; ++kk)
      #pragma unroll
      for (int m = 0; m < 4; ++m)
        #pragma unroll
        for (int n = 0; n < 2; ++n)
          acc[m][n] = __builtin_amdgcn_mfma_f32_16x16x32_bf16(af[m][kk], bfg[n][kk], acc[m][n], 0, 0, 0);
    #pragma unroll
    for (int m = 0; m < 4; ++m)
      #pragma unroll
      for (int n = 0; n < 2; ++n) {
        int col = w * 32 + n * 16 + lrow;
        #pragma unroll
        for (int reg = 0; reg < 4; ++reg) {
          int lr = m * 16 + (lane >> 4) * 4 + reg;
          int row = row0 + lr;
          if (row < M) hg[(size_t)row * D + col] = f2bf(sdinv[lr] * acc[m][n][reg]);
        }
      }
  }
  __syncthreads();
  #pragma unroll
  for (int j = 0; j < 8; ++j) {
    int idx = tid + j * 256;
    int nr = idx >> 4, c = idx & 15;
    *(short8*)&Bs[swz(nr, c * 8)] = *(const short8*)(Wlt + nr * D + c * 8);
  }
  __syncthreads();
  // ---- phase l (+ folded biases) ----
  {
    short8 bfl[2][4];
    #pragma unroll
    for (int n = 0; n < 2; ++n) {
      int br = w * 32 + n * 16 + lrow;
      #pragma unroll
      for (int kk = 0; kk < 4; ++kk)
        bfl[n][kk] = *(const short8*)&Bs[swz(br, lk + kk * 32)];
    }
    floatx4 acc[4][2];
    #pragma unroll
    for (int m = 0; m < 4; ++m)
      #pragma unroll
      for (int n = 0; n < 2; ++n)
        acc[m][n] = (floatx4)0.0f;
    #pragma unroll
    for (int kk = 0; kk < 4; ++kk)
      #pragma unroll
      for (int m = 0; m < 4; ++m)
        #pragma unroll
        for (int n = 0; n < 2; ++n)
          acc[m][n] = __builtin_amdgcn_mfma_f32_16x16x32_bf16(af[m][kk], bfl[n][kk], acc[m][n], 0, 0, 0);
    #pragma unroll
    for (int m = 0; m < 4; ++m)
      #pragma unroll
      for (int n = 0; n < 2; ++n) {
        int col = w * 32 + n * 16 + lrow;
        float bias = bg[col] + bl[col];
        #pragma unroll
        for (int reg = 0; reg < 4; ++reg) {
          int row = row0 + m * 16 + (lane >> 4) * 4 + reg;
          if (row < M) hl[(size_t)row * D + col] = f2bf(acc[m][n][reg] + bias);
        }
      }
  }
}

// ---------------- aggregation (+ fused BN partial stats): 16 nodes/block, 4/wave (R10 version) ----------------
// hg2 pre-scaled by dinv[src]; 8-deep gather pipeline, masked single tail group
__global__ __launch_bounds__(256) void k_agg(const unsigned short* __restrict__ hg2, unsigned short* __restrict__ pre,
                                             const int* __restrict__ rowstart, const int* __restrict__ csr,
                                             const float* __restrict__ dinv,
                                             float* __restrict__ partial, int n) {
  int t = threadIdx.x, b = blockIdx.x;
  int w = t >> 6, lane = t & 63;
  const unsigned int* base = (const unsigned int*)hg2;  // 2 bf16 per dword
  unsigned int* prew = (unsigned int*)pre;
  float st_s0 = 0.f, st_s1 = 0.f, st_q0 = 0.f, st_q1 = 0.f;
  int c = lane * 2;
  int node0 = b * 16 + w * 4;
  #pragma unroll 1
  for (int k = 0; k < 4; ++k) {
    int node = node0 + k;
    if (node >= n) break;
    int s = rowstart[node], e = rowstart[node + 1];
    float dn = dinv[node];
    unsigned int ps = base[(size_t)node * 64 + lane];      // hg2 self = dinv*hg
    unsigned int oldw = prew[(size_t)node * 64 + lane];
    float A0 = 0.f, A1 = 0.f, B0 = 0.f, B1 = 0.f, C0 = 0.f, C1 = 0.f, D0 = 0.f, D1 = 0.f;
    float E0 = 0.f, E1 = 0.f, F0 = 0.f, F1 = 0.f, G0 = 0.f, G1 = 0.f, H0 = 0.f, H1 = 0.f;
    int j = s;
    for (; j + 8 <= e; j += 8) {
      int i0 = csr[j],     i1 = csr[j + 1], i2 = csr[j + 2], i3 = csr[j + 3];
      int i4 = csr[j + 4], i5 = csr[j + 5], i6 = csr[j + 6], i7 = csr[j + 7];
      unsigned int p0 = base[(size_t)i0 * 64 + lane];
      unsigned int p1 = base[(size_t)i1 * 64 + lane];
      unsigned int p2 = base[(size_t)i2 * 64 + lane];
      unsigned int p3 = base[(size_t)i3 * 64 + lane];
      unsigned int p4 = base[(size_t)i4 * 64 + lane];
      unsigned int p5 = base[(size_t)i5 * 64 + lane];
      unsigned int p6 = base[(size_t)i6 * 64 + lane];
      unsigned int p7 = base[(size_t)i7 * 64 + lane];
      A0 += __uint_as_float(p0 << 16); A1 += __uint_as_float(p0 & 0xFFFF0000u);
      B0 += __uint_as_float(p1 << 16); B1 += __uint_as_float(p1 & 0xFFFF0000u);
      C0 += __uint_as_float(p2 << 16); C1 += __uint_as_float(p2 & 0xFFFF0000u);
      D0 += __uint_as_float(p3 << 16); D1 += __uint_as_float(p3 & 0xFFFF0000u);
      E0 += __uint_as_float(p4 << 16); E1 += __uint_as_float(p4 & 0xFFFF0000u);
      F0 += __uint_as_float(p5 << 16); F1 += __uint_as_float(p5 & 0xFFFF0000u);
      G0 += __uint_as_float(p6 << 16); G1 += __uint_as_float(p6 & 0xFFFF0000u);
      H0 += __uint_as_float(p7 << 16); H1 += __uint_as_float(p7 & 0xFFFF0000u);
    }
    if (j < e) {
      // one masked 8-group for the tail (clamped index; duplicates hit L1)
      int last = e - 1;
      int t0 = csr[j];
      int t1 = csr[min(j + 1, last)], t2 = csr[min(j + 2, last)], t3 = csr[min(j + 3, last)];
      int t4 = csr[min(j + 4, last)], t5 = csr[min(j + 5, last)], t6 = csr[min(j + 6, last)];
      unsigned int p0 = base[(size_t)t0 * 64 + lane];
      unsigned int p1 = base[(size_t)t1 * 64 + lane];
      unsigned int p2 = base[(size_t)t2 * 64 + lane];
      unsigned int p3 = base[(size_t)t3 * 64 + lane];
      unsigned int p4 = base[(size_t)t4 * 64 + lane];
      unsigned int p5 = base[(size_t)t5 * 64 + lane];
      unsigned int p6 = base[(size_t)t6 * 64 + lane];
      int r = e - j;   // 1..7 valid
      A0 += __uint_as_float(p0 << 16);                     A1 += __uint_as_float(p0 & 0xFFFF0000u);
      if (r > 1) { B0 += __uint_as_float(p1 << 16);        B1 += __uint_as_float(p1 & 0xFFFF0000u); }
      if (r > 2) { C0 += __uint_as_float(p2 << 16);        C1 += __uint_as_float(p2 & 0xFFFF0000u); }
      if (r > 3) { D0 += __uint_as_float(p3 << 16);        D1 += __uint_as_float(p3 & 0xFFFF0000u); }
      if (r > 4) { E0 += __uint_as_float(p4 << 16);        E1 += __uint_as_float(p4 & 0xFFFF0000u); }
      if (r > 5) { F0 += __uint_as_float(p5 << 16);        F1 += __uint_as_float(p5 & 0xFFFF0000u); }
      if (r > 6) { G0 += __uint_as_float(p6 << 16);        G1 += __uint_as_float(p6 & 0xFFFF0000u); }
    }
    float acc0 = ((A0 + B0) + (C0 + D0)) + ((E0 + F0) + (G0 + H0));
    float acc1 = ((A1 + B1) + (C1 + D1)) + ((E1 + F1) + (G1 + H1));
    float h0 = __uint_as_float(ps << 16);
    float h1 = __uint_as_float(ps & 0xFFFF0000u);
    float old0 = __uint_as_float(oldw << 16);
    float old1 = __uint_as_float(oldw & 0xFFFF0000u);
    float p0v = dn * (acc0 + h0) + old0;   // old already includes bg+bl
    float p1v = dn * (acc1 + h1) + old1;
    prew[(size_t)node * 64 + lane] = (unsigned int)f2bf(p0v) | ((unsigned int)f2bf(p1v) << 16);
    st_s0 += p0v; st_s1 += p1v;            // stats from f32 pre-rounding values
    st_q0 += p0v * p0v; st_q1 += p1v * p1v;
  }
  __shared__ float sm[4][128], sq[4][128];
  sm[w][c] = st_s0; sm[w][c + 1] = st_s1;
  sq[w][c] = st_q0; sq[w][c + 1] = st_q1;
  __syncthreads();
  if (t < 128) {
    float s = (sm[0][t] + sm[1][t]) + (sm[2][t] + sm[3][t]);
    float q = (sq[0][t] + sq[1][t]) + (sq[2][t] + sq[3][t]);
    partial[(size_t)b * 256 + t] = s;          // row-major: contiguous 1KB per block
    partial[(size_t)b * 256 + 128 + t] = q;
  }
}

// ---------------- BN reduce stage A: 64 blocks, coalesced column sums over partial rows ----------------
__global__ __launch_bounds__(256) void k_fina(const float* __restrict__ partial, float* __restrict__ p2, int nab) {
  int t = threadIdx.x, b = blockIdx.x;
  float s = 0.f;
  for (int i = b; i < nab; i += 64)
    s += partial[(size_t)i * 256 + t];
  p2[(size_t)b * 256 + t] = s;
}

// ---------------- BN reduce stage B: 1 block, final sum + affine ----------------
__global__ __launch_bounds__(256) void k_finb(const float* __restrict__ p2,
                                              const float* __restrict__ gamma, const float* __restrict__ beta,
                                              float* __restrict__ ab, float invN) {
  int t = threadIdx.x;
  float s = 0.f;
  #pragma unroll
  for (int b = 0; b < 64; ++b)
    s += p2[(size_t)b * 256 + t];
  __shared__ float red[256];
  red[t] = s;
  __syncthreads();
  if (t < 128) {
    float mean = red[t] * invN;
    float var = red[128 + t] * invN - mean * mean;
    float inv = rsqrtf(var + 1e-5f);
    float g = gamma[t];
    ab[t] = g * inv;
    ab[128 + t] = beta[t] - mean * inv * g;
  }
}

// ---------------- fused: h=BN+ReLU(pre bf16); out(+)=h@Wp(+bp); hg2=dinv*(h@Wg_next); hl=h@Wl_next+biases ----------------
template<bool FIRST>
__global__ __launch_bounds__(256) void k_fused(const unsigned short* __restrict__ pre, const float* __restrict__ ab,
                                               const unsigned short* __restrict__ Wpt, const float* __restrict__ bp,
                                               const unsigned short* __restrict__ Wgt,
                                               const unsigned short* __restrict__ Wlt,
                                               const float* __restrict__ bgn, const float* __restrict__ bln,
                                               const float* __restrict__ dinv,
                                               float* __restrict__ out, unsigned short* __restrict__ hg,
                                               unsigned short* __restrict__ hl, int M) {
  __shared__ unsigned short As[64 * 128];   // 16 KB
  __shared__ unsigned short Bs[128 * 128];  // 32 KB (Wp then Wg then Wl)
  __shared__ float sdinv[64];
  int tid = threadIdx.x;
  int row0 = blockIdx.x * 64;

  if (tid < 64) sdinv[tid] = (row0 + tid < M) ? dinv[row0 + tid] : 0.f;
  // stage A: h tile from bf16 pre + BN affine + relu (swizzled)
  {
    int r = tid >> 2, qq = tid & 3;
    int row = row0 + r;
    bool valid = row < M;
    const unsigned short* Pp = pre + (size_t)row * D;
    #pragma unroll
    for (int ch = 0; ch < 4; ++ch) {
      int k0 = qq * 32 + ch * 8;
      short8 pv = {0, 0, 0, 0, 0, 0, 0, 0};
      if (valid) pv = *(const short8*)(Pp + k0);
      float4 a0 = *(const float4*)(ab + k0),        a1 = *(const float4*)(ab + k0 + 4);
      float4 b0 = *(const float4*)(ab + 128 + k0),  b1 = *(const float4*)(ab + 128 + k0 + 4);
      float av[8] = {a0.x, a0.y, a0.z, a0.w, a1.x, a1.y, a1.z, a1.w};
      float bv[8] = {b0.x, b0.y, b0.z, b0.w, b1.x, b1.y, b1.z, b1.w};
      unsigned short hv[8];
      #pragma unroll
      for (int jj = 0; jj < 8; ++jj) {
        float f = bf2f((unsigned short)pv[jj]);
        hv[jj] = f2bf(fmaxf(f * av[jj] + bv[jj], 0.f));
      }
      *(short8*)&As[swz(r, k0)] = *(const short8*)hv;
    }
  }
  // stage Wp^T [64][128]
  #pragma unroll
  for (int j = 0; j < 4; ++j) {
    int idx = tid + j * 256;
    int nr = idx >> 4, c = idx & 15;
    *(short8*)&Bs[swz(nr, c * 8)] = *(const short8*)(Wpt + nr * D + c * 8);
  }
  __syncthreads();

  int lane = tid & 63, w = tid >> 6;
  int lrow = lane & 15, lk = (lane >> 4) * 8;

  short8 af[4][4];
  #pragma unroll
  for (int m = 0; m < 4; ++m) {
    int ar = lrow + m * 16;
    #pragma unroll
    for (int kk = 0; kk < 4; ++kk)
      af[m][kk] = *(const short8*)&As[swz(ar, lk + kk * 32)];
  }

  // ---- phase P: out ----
  {
    short8 bfr[4];
    int br = w * 16 + lrow;
    #pragma unroll
    for (int kk = 0; kk < 4; ++kk)
      bfr[kk] = *(const short8*)&Bs[swz(br, lk + kk * 32)];
    floatx4 acc[4];
    #pragma unroll
    for (int m = 0; m < 4; ++m) acc[m] = (floatx4)0.0f;
    #pragma unroll
    for (int kk = 0; kk < 4; ++kk)
      #pragma unroll
      for (int m = 0; m < 4; ++m)
        acc[m] = __builtin_amdgcn_mfma_f32_16x16x32_bf16(af[m][kk], bfr[kk], acc[m], 0, 0, 0);
    int col = w * 16 + lrow;
    float bpv = FIRST ? bp[col] : 0.f;
    #pragma unroll
    for (int m = 0; m < 4; ++m)
      #pragma unroll
      for (int reg = 0; reg < 4; ++reg) {
        int row = row0 + m * 16 + (lane >> 4) * 4 + reg;
        if (row < M) {
          float* op = &out[(size_t)row * OUTC + col];
          float v = acc[m][reg] + bpv;
          if (!FIRST) v += *op;
          *op = v;
        }
      }
  }
  __syncthreads();
  // stage Wg^T
  #pragma unroll
  for (int j = 0; j < 8; ++j) {
    int idx = tid + j * 256;
    int nr = idx >> 4, c = idx & 15;
    *(short8*)&Bs[swz(nr, c * 8)] = *(const short8*)(Wgt + nr * D + c * 8);
  }
  __syncthreads();
  // ---- phase G: hg2 = dinv * (h@Wg) ----
  {
    short8 bfg[2][4];
    #pragma unroll
    for (int n = 0; n < 2; ++n) {
      int br = w * 32 + n * 16 + lrow;
      #pragma unroll
      for (int kk = 0; kk < 4; ++kk)
        bfg[n][kk] = *(const short8*)&Bs[swz(br, lk + kk * 32)];
    }
    floatx4 acc[4][2];
    #pragma unroll
    for (int m = 0; m < 4; ++m)
      #pragma unroll
      for (int n = 0; n < 2; ++n)
        acc[m][n] = (floatx4)0.0f;
    #pragma unroll
    for (int kk = 0; kk < 4; ++kk)
      #pragma unroll
      for (int m = 0; m < 4; ++m)
        #pragma unroll
        for (int n = 0; n < 2; ++n)
          acc[m][n] = __builtin_amdgcn_mfma_f32_16x16x32_bf16(af[m][kk], bfg[n][kk], acc[m][n], 0, 0, 0);
    #pragma unroll
    for (int m = 0; m < 4; ++m)
      #pragma unroll
      for (int n = 0; n < 2; ++n) {
        int col = w * 32 + n * 16 + lrow;
        #pragma unroll
        for (int reg = 0; reg < 4; ++reg) {
          int lr = m * 16 + (lane >> 4) * 4 + reg;
          int row = row0 + lr;
          if (row < M) hg[(size_t)row * D + col] = f2bf(sdinv[lr] * acc[m][n][reg]);
        }
      }
  }
  __syncthreads();
  // stage Wl^T
  #pragma unroll
  for (int j = 0; j < 8; ++j) {
    int idx = tid + j * 256;
    int nr = idx >> 4, c = idx & 15;
    *(short8*)&Bs[swz(nr, c * 8)] = *(const short8*)(Wlt + nr * D + c * 8);
  }
  __syncthreads();
  // ---- phase L: hl (in-place over pre rows of THIS block only) ----
  {
    short8 bfl[2][4];
    #pragma unroll
    for (int n = 0; n < 2; ++n) {
      int br = w * 32 + n * 16 + lrow;
      #pragma unroll
      for (int kk = 0; kk < 4; ++kk)
        bfl[n][kk] = *(const short8*)&Bs[swz(br, lk + kk * 32)];
    }
    floatx4 acc[4][2];
    #pragma unroll
    for (int m = 0; m < 4; ++m)
      #pragma unroll
      for (int n = 0; n < 2; ++n)
        acc[m][n] = (floatx4)0.0f;
    #pragma unroll
    for (int kk = 0; kk < 4; ++kk)
      #pragma unroll
      for (int m = 0; m < 4; ++m)
        #pragma unroll
        for (int n = 0; n < 2; ++n)
          acc[m][n] = __builtin_amdgcn_mfma_f32_16x16x32_bf16(af[m][kk], bfl[n][kk], acc[m][n], 0, 0, 0);
    #pragma unroll
    for (int m = 0; m < 4; ++m)
      #pragma unroll
      for (int n = 0; n < 2; ++n) {
        int col = w * 32 + n * 16 + lrow;
        float bias = bgn[col] + bln[col];
        #pragma unroll
        for (int reg = 0; reg < 4; ++reg) {
          int row = row0 + m * 16 + (lane >> 4) * 4 + reg;
          if (row < M) hl[(size_t)row * D + col] = f2bf(acc[m][n][reg] + bias);
        }
      }
  }
}

// ---------------- final layer: h=BN+ReLU(pre bf16); out += h@Wp ----------------
__global__ __launch_bounds__(256) void k_out(const unsigned short* __restrict__ pre, const float* __restrict__ ab,
                                             const unsigned short* __restrict__ Wpt,
                                             float* __restrict__ out, int M) {
  __shared__ unsigned short As[64 * 128];   // 16 KB
  __shared__ unsigned short Bs[OUTC * 128]; // 16 KB
  int tid = threadIdx.x;
  int row0 = blockIdx.x * 64;

  {
    int r = tid >> 2, qq = tid & 3;
    int row = row0 + r;
    bool valid = row < M;
    const unsigned short* Pp = pre + (size_t)row * D;
    #pragma unroll
    for (int ch = 0; ch < 4; ++ch) {
      int k0 = qq * 32 + ch * 8;
      short8 pv = {0, 0, 0, 0, 0, 0, 0, 0};
      if (valid) pv = *(const short8*)(Pp + k0);
      float4 a0 = *(const float4*)(ab + k0),        a1 = *(const float4*)(ab + k0 + 4);
      float4 b0 = *(const float4*)(ab + 128 + k0),  b1 = *(const float4*)(ab + 128 + k0 + 4);
      float av[8] = {a0.x, a0.y, a0.z, a0.w, a1.x, a1.y, a1.z, a1.w};
      float bv[8] = {b0.x, b0.y, b0.z, b0.w, b1.x, b1.y, b1.z, b1.w};
      unsigned short hv[8];
      #pragma unroll
      for (int jj = 0; jj < 8; ++jj) {
        float f = bf2f((unsigned short)pv[jj]);
        hv[jj] = f2bf(fmaxf(f * av[jj] + bv[jj], 0.f));
      }
      *(short8*)&As[swz(r, k0)] = *(const short8*)hv;
    }
  }
  #pragma unroll
  for (int j = 0; j < 4; ++j) {
    int idx = tid + j * 256;
    int nr = idx >> 4, c = idx & 15;
    *(short8*)&Bs[swz(nr, c * 8)] = *(const short8*)(Wpt + nr * D + c * 8);
  }
  __syncthreads();

  int lane = tid & 63, w = tid >> 6;
  int lrow = lane & 15, lk = (lane >> 4) * 8;

  short8 af[4][4];
  #pragma unroll
  for (int m = 0; m < 4; ++m) {
    int ar = lrow + m * 16;
    #pragma unroll
    for (int kk = 0; kk < 4; ++kk)
      af[m][kk] = *(const short8*)&As[swz(ar, lk + kk * 32)];
  }
  short8 bfr[4];
  {
    int br = w * 16 + lrow;
    #pragma unroll
    for (int kk = 0; kk < 4; ++kk)
      bfr[kk] = *(const short8*)&Bs[swz(br, lk + kk * 32)];
  }
  floatx4 acc[4];
  #pragma unroll
  for (int m = 0; m < 4; ++m) acc[m] = (floatx4)0.0f;
  #pragma unroll
  for (int kk = 0; kk < 4; ++kk)
    #pragma unroll
    for (int m = 0; m < 4; ++m)
      acc[m] = __builtin_amdgcn_mfma_f32_16x16x32_bf16(af[m][kk], bfr[kk], acc[m], 0, 0, 0);

  int col = w * 16 + lrow;
  #pragma unroll
  for (int m = 0; m < 4; ++m)
    #pragma unroll
    for (int reg = 0; reg < 4; ++reg) {
      int row = row0 + m * 16 + (lane >> 4) * 4 + reg;
      if (row < M) {
        float* op = &out[(size_t)row * OUTC + col];
        *op = *op + acc[m][reg];
      }
    }
}

extern "C" void kernel_launch(void* const* d_in, const int* in_sizes, int n_in,
                              void* d_out, int out_size, void* d_ws, size_t ws_size,
                              hipStream_t stream) {
  const float* x     = (const float*)d_in[0];
  const int*   ei    = (const int*)d_in[1];
  const float* Wg    = (const float*)d_in[2];
  const float* bg    = (const float*)d_in[3];
  const float* Wl    = (const float*)d_in[4];
  const float* bl    = (const float*)d_in[5];
  const float* gamma = (const float*)d_in[6];
  const float* beta  = (const float*)d_in[7];
  const float* Wp    = (const float*)d_in[8];
  const float* bp    = (const float*)d_in[9];
  float* out = (float*)d_out;

  int N = in_sizes[0] / D;
  int E = in_sizes[1] / 2;
  const int* srcp = ei;
  const int* dstp = ei + E;

  char* wsb = (char*)d_ws;
  size_t off = 0;
  auto alloc = [&](size_t bytes) {
    off = (off + 255) & ~(size_t)255;
    void* p = wsb + off;
    off += bytes;
    return p;
  };
  int nab = (N + 15) / 16;                 // k_agg blocks (16 nodes/block, 4/wave)
  float* dinv     = (float*)alloc((size_t)N * 4);
  int*   rowstart = (int*)alloc((size_t)(N + 1) * 4);
  int*   csr      = (int*)alloc((size_t)E * 4);
  int*   bh       = (int*)alloc((size_t)256 * EC * 4);
  unsigned int* ebuk = (unsigned int*)alloc((size_t)E * 4);
  int*   bsum     = (int*)alloc(1024 * 4);
  float* partial  = (float*)alloc((size_t)nab * 256 * 4);   // [block][256] row-major
  float* p2       = (float*)alloc((size_t)64 * 256 * 4);
  float* ab       = (float*)alloc(3 * 256 * 4);
  unsigned short* hg  = (unsigned short*)alloc((size_t)N * D * 2);
  unsigned short* hl  = (unsigned short*)alloc((size_t)N * D * 2);
  unsigned short* Wgt = (unsigned short*)alloc(3 * D * D * 2);
  unsigned short* Wlt = (unsigned short*)alloc(3 * D * D * 2);
  unsigned short* Wpt = (unsigned short*)alloc(D * OUTC * 2);
  (void)ws_size; (void)n_in; (void)out_size;

  int wtotal = 2 * 3 * D * D + D * OUTC;
  k_prepw<<<(wtotal + 255) / 256, 256, 0, stream>>>(Wg, Wl, Wp, Wgt, Wlt, Wpt);

  // ---- CSR build (atomic-free counting sort) ----
  int nbuk = (N + 255) >> 8;
  int chk  = (E + EC - 1) / EC;
  k_bh<<<EC, 256, 0, stream>>>(dstp, bh, E, nbuk, chk);
  int sn  = nbuk * EC;
  int snb = (sn + 1023) >> 10;
  k_gscan1<<<snb, 256, 0, stream>>>(bh, bsum, sn);
  k_gscan2<<<1, 256, 0, stream>>>(bsum, snb);
  k_scatter<<<EC, 256, 0, stream>>>(srcp, dstp, bh, bsum, ebuk, E, nbuk, chk);
  k_csr<<<nbuk, 256, 0, stream>>>(ebuk, bh, bsum, rowstart, csr, dinv, E, N, nbuk);

  int mt = (N + 63) / 64;
  float invN = 1.0f / (float)N;

  // layer 0 GEMMs (reads x f32 directly)
  k_dual<<<mt, 256, 0, stream>>>(x, Wgt, Wlt, bg, bl, dinv, hg, hl, N);

  for (int i = 0; i < 3; ++i) {
    k_agg<<<nab, 256, 0, stream>>>(hg, hl, rowstart, csr, dinv, partial, N);
    k_fina<<<64, 256, 0, stream>>>(partial, p2, nab);
    k_finb<<<1, 256, 0, stream>>>(p2, gamma + (size_t)i * D, beta + (size_t)i * D, ab + i * 256, invN);
    if (i == 0)
      k_fused<true><<<mt, 256, 0, stream>>>(hl, ab + i * 256, Wpt, bp,
                                            Wgt + (size_t)(i + 1) * D * D, Wlt + (size_t)(i + 1) * D * D,
                                            bg + (size_t)(i + 1) * D, bl + (size_t)(i + 1) * D,
                                            dinv, out, hg, hl, N);
    else if (i == 1)
      k_fused<false><<<mt, 256, 0, stream>>>(hl, ab + i * 256, Wpt, bp,
                                             Wgt + (size_t)(i + 1) * D * D, Wlt + (size_t)(i + 1) * D * D,
                                             bg + (size_t)(i + 1) * D, bl + (size_t)(i + 1) * D,
                                             dinv, out, hg, hl, N);
    else
      k_out<<<mt, 256, 0, stream>>>(hl, ab + i * 256, Wpt, out, N);
  }
}